// Round 7
// baseline (391.402 us; speedup 1.0000x reference)
//
#include <hip/hip_runtime.h>

#define BB 64
#define HH 512
#define WW 512
#define PLANE (HH * WW)
#define R 64
#define NSTRIPE (HH / R)        // 8
#define N_CHEBY 15

struct Sl { float a, b, c, d; };

__device__ __forceinline__ void racc(const Sl& s, float k0, float k1, float k2,
                                     float& o0, float& o1) {
    o0 = fmaf(k0, s.a, fmaf(k1, s.b, fmaf(k2, s.c, o0)));
    o1 = fmaf(k0, s.b, fmaf(k1, s.c, fmaf(k2, s.d, o1)));
}

__device__ __forceinline__ Sl ldsl(const float* pl, int row, int c2, bool ok) {
    Sl s = {0.f, 0.f, 0.f, 0.f};
    if (ok) {
        const float* rp = pl + (size_t)row * WW;
        float2 v = *reinterpret_cast<const float2*>(rp + c2);
        s.b = v.x; s.c = v.y;
        if (c2 > 0)      s.a = rp[c2 - 1];
        if (c2 + 2 < WW) s.d = rp[c2 + 2];
    }
    return s;
}

// Barrier WITHOUT vmcnt drain: flush LDS ops, leave global loads in flight.
__device__ __forceinline__ void softbar() {
    __asm__ volatile("s_waitcnt lgkmcnt(0)" ::: "memory");
    __builtin_amdgcn_s_barrier();
}

// ---------------------------------------------------------------------------
// Fused FDv-level power pass: v1 = inv*A(in), v_{j+1} = A(v_j).
// mz = stripe max|v_{FDv-1}|, mw = stripe max|v_FDv|. out==null -> no store.
// ---------------------------------------------------------------------------
template<int FDv>
__global__ __launch_bounds__(256, 2) void conv_fusedN(
    const float* __restrict__ in, const float* __restrict__ kern,
    const float* __restrict__ pm_prev, float* __restrict__ out,
    float* __restrict__ pmw, float* __restrict__ pmz)
{
    const int b = blockIdx.y, stripe = blockIdx.x, ytop = stripe * R;
    const int t = threadIdx.x, c2 = t << 1;

    __shared__ float re[FDv - 1][2][258], ro[FDv - 1][2][258];
    __shared__ float sred[8];
    __shared__ float sinv;

    if (t < 2 * (FDv - 1)) {
        const int l = t >> 1, par = t & 1;
        re[l][par][0] = 0.f; re[l][par][257] = 0.f;
        ro[l][par][0] = 0.f; ro[l][par][257] = 0.f;
    }
    if (pm_prev && t < 64) {
        float v = (t < NSTRIPE) ? pm_prev[b * NSTRIPE + t] : 0.f;
#pragma unroll
        for (int o = 8; o; o >>= 1) v = fmaxf(v, __shfl_xor(v, o, 64));
        if (t == 0) sinv = 1.f / v;
    }
    __syncthreads();
    const float invv = pm_prev ? sinv : 1.f;

    const float* kb = kern + b * 9;
    const float k00=kb[0],k01=kb[1],k02=kb[2],k10=kb[3],k11=kb[4],k12=kb[5],
                k20=kb[6],k21=kb[7],k22=kb[8];
    const float* ip = in + (size_t)b * PLANE;
    float* op = out ? out + (size_t)b * PLANE : nullptr;

    Sl u2 = {0,0,0,0}, u1 = {0,0,0,0};
    Sl ltp[FDv - 1], lmd[FDv - 1];
    float own0[FDv - 1], own1[FDv - 1];
#pragma unroll
    for (int l = 0; l < FDv - 1; ++l) {
        ltp[l] = Sl{0,0,0,0}; lmd[l] = Sl{0,0,0,0};
        own0[l] = 0.f; own1[l] = 0.f;
    }
    float mz = 0.f, mw = 0.f;
    Sl u0 = ldsl(ip, ytop - FDv, c2, (unsigned)(ytop - FDv) < HH);

    const int STEPS   = R + 3 * FDv - 1;
    const int LOADCUT = R + 2 * FDv - 1;
#pragma unroll 2
    for (int p = 0; p < STEPS; ++p) {
        const int yu = ytop - FDv + p;
        Sl un = ldsl(ip, yu + 1, c2, ((unsigned)(yu + 1) < HH) && (p < LOADCUT));

        const int rpar = (p + 1) & 1, wpar = p & 1;
        Sl am[FDv - 1];
#pragma unroll
        for (int l = 0; l < FDv - 1; ++l) {
            am[l].a = ro[l][rpar][t];
            am[l].b = own0[l];
            am[l].c = own1[l];
            am[l].d = re[l][rpar][2 + t];
        }

        float v0[FDv], v1[FDv];
        {   // level 1 (normalized)
            float s0 = 0.f, s1 = 0.f;
            racc(u2, k00,k01,k02, s0,s1);
            racc(u1, k10,k11,k12, s0,s1);
            racc(u0, k20,k21,k22, s0,s1);
            const int y = yu - 1;
            const bool act = (y >= ytop - (FDv-1)) && (y <= ytop + R + FDv - 2)
                          && ((unsigned)y < HH);
            v0[0] = act ? s0 * invv : 0.f;
            v1[0] = act ? s1 * invv : 0.f;
        }
#pragma unroll
        for (int j = 2; j <= FDv; ++j) {
            float s0 = 0.f, s1 = 0.f;
            racc(ltp[j-2], k00,k01,k02, s0,s1);
            racc(lmd[j-2], k10,k11,k12, s0,s1);
            racc(am[j-2],  k20,k21,k22, s0,s1);
            const int y = yu - (2*j - 1);
            if (j < FDv) {
                const bool act = (y >= ytop - (FDv-j)) && (y <= ytop + R + FDv - j - 1)
                              && ((unsigned)y < HH);
                v0[j-1] = act ? s0 : 0.f;
                v1[j-1] = act ? s1 : 0.f;
                if (j == FDv - 1)
                    mz = fmaxf(mz, fmaxf(fabsf(v0[j-1]), fabsf(v1[j-1])));
            } else {
                if (y >= ytop && y < ytop + R) {
                    mw = fmaxf(mw, fmaxf(fabsf(s0), fabsf(s1)));
                    if (op)
                        *reinterpret_cast<float2*>(op + (size_t)y * WW + c2) =
                            make_float2(s0, s1);
                }
            }
        }
#pragma unroll
        for (int l = 0; l < FDv - 1; ++l) {
            re[l][wpar][1 + t] = v0[l];
            ro[l][wpar][1 + t] = v1[l];
            ltp[l] = lmd[l]; lmd[l] = am[l];
            own0[l] = v0[l]; own1[l] = v1[l];
        }
        u2 = u1; u1 = u0; u0 = un;
        softbar();
    }

#pragma unroll
    for (int o = 32; o; o >>= 1) {
        mz = fmaxf(mz, __shfl_xor(mz, o, 64));
        mw = fmaxf(mw, __shfl_xor(mw, o, 64));
    }
    if ((t & 63) == 0) { sred[t >> 6] = mz; sred[4 + (t >> 6)] = mw; }
    __syncthreads();
    if (t == 0) {
        pmz[b * NSTRIPE + stripe] =
            fmaxf(fmaxf(sred[0], sred[1]), fmaxf(sred[2], sred[3]));
        pmw[b * NSTRIPE + stripe] =
            fmaxf(fmaxf(sred[4], sred[5]), fmaxf(sred[6], sred[7]));
    }
}

// ---------------------------------------------------------------------------
// m = max|v_FD| / max|v_{FD-1}| of final power pass; taus[it*BB+b].
// ---------------------------------------------------------------------------
__global__ __launch_bounds__(64) void tau_fused(
    const float* __restrict__ pmz, const float* __restrict__ pmw,
    float* __restrict__ taus)
{
    const int b = blockIdx.x, t = threadIdx.x;
    float vz = (t < NSTRIPE) ? pmz[b * NSTRIPE + t] : 0.f;
    float vw = (t < NSTRIPE) ? pmw[b * NSTRIPE + t] : 0.f;
#pragma unroll
    for (int o = 8; o; o >>= 1) {
        vz = fmaxf(vz, __shfl_xor(vz, o, 64));
        vw = fmaxf(vw, __shfl_xor(vw, o, 64));
    }
    if (t < N_CHEBY) {
        const float m = vw / vz;
        const double rr = cos(M_PI * (2.0 * t + 1.0) / (2.0 * N_CHEBY));
        const float denom = m + m / 3.0f - (m / 3.0f - m) * (float)rr;
        taus[t * BB + b] = 2.0f / denom;
    }
}

// ---------------------------------------------------------------------------
// Fused FDv-level Chebyshev pass: x_j = x_{j-1} + tau_{j-1}*(f - A x_{j-1}).
// f carried in a (2*FDv-1)-deep register ring; level j uses fh[2(j-1)].
// ---------------------------------------------------------------------------
template<int FDv>
__global__ __launch_bounds__(256, 2) void cheby_fusedN(
    const float* __restrict__ xin, const float* __restrict__ fin,
    const float* __restrict__ kern, const float* __restrict__ tauv,
    float* __restrict__ xout)
{
    const int b = blockIdx.y, stripe = blockIdx.x, ytop = stripe * R;
    const int t = threadIdx.x, c2 = t << 1;

    __shared__ float re[FDv - 1][2][258], ro[FDv - 1][2][258];

    if (t < 2 * (FDv - 1)) {
        const int l = t >> 1, par = t & 1;
        re[l][par][0] = 0.f; re[l][par][257] = 0.f;
        ro[l][par][0] = 0.f; ro[l][par][257] = 0.f;
    }
    __syncthreads();

    const float* kb = kern + b * 9;
    const float k00=kb[0],k01=kb[1],k02=kb[2],k10=kb[3],k11=kb[4],k12=kb[5],
                k20=kb[6],k21=kb[7],k22=kb[8];
    float tau[FDv];
#pragma unroll
    for (int j = 0; j < FDv; ++j) tau[j] = tauv[j * BB + b];

    const float* xp = xin + (size_t)b * PLANE;
    const float* fp = fin + (size_t)b * PLANE;
    float* op = xout + (size_t)b * PLANE;

    Sl u2 = {0,0,0,0}, u1 = {0,0,0,0};
    Sl ltp[FDv - 1], lmd[FDv - 1];
    float own0[FDv - 1], own1[FDv - 1];
#pragma unroll
    for (int l = 0; l < FDv - 1; ++l) {
        ltp[l] = Sl{0,0,0,0}; lmd[l] = Sl{0,0,0,0};
        own0[l] = 0.f; own1[l] = 0.f;
    }
    float2 fh[2 * FDv - 1];
#pragma unroll
    for (int k = 1; k < 2 * FDv - 1; ++k) fh[k] = make_float2(0.f, 0.f);

    Sl u0 = ldsl(xp, ytop - FDv, c2, (unsigned)(ytop - FDv) < HH);
    {
        const int yf = ytop - FDv - 1;
        fh[0] = ((unsigned)yf < HH)
            ? *reinterpret_cast<const float2*>(fp + (size_t)yf * WW + c2)
            : make_float2(0.f, 0.f);
    }

    const int STEPS   = R + 3 * FDv - 1;
    const int LOADCUT = R + 2 * FDv - 1;
#pragma unroll 2
    for (int p = 0; p < STEPS; ++p) {
        const int yu = ytop - FDv + p;
        const bool ldok = (p < LOADCUT);
        Sl un = ldsl(xp, yu + 1, c2, ((unsigned)(yu + 1) < HH) && ldok);
        const float2 fn = (((unsigned)yu < HH) && ldok)
            ? *reinterpret_cast<const float2*>(fp + (size_t)yu * WW + c2)
            : make_float2(0.f, 0.f);

        const int rpar = (p + 1) & 1, wpar = p & 1;
        Sl am[FDv - 1];
#pragma unroll
        for (int l = 0; l < FDv - 1; ++l) {
            am[l].a = ro[l][rpar][t];
            am[l].b = own0[l];
            am[l].c = own1[l];
            am[l].d = re[l][rpar][2 + t];
        }

        float v0[FDv], v1[FDv];
        {   // level 1: x1 = x + tau0*(f - A x)   at row yu-1
            float s0 = 0.f, s1 = 0.f;
            racc(u2, k00,k01,k02, s0,s1);
            racc(u1, k10,k11,k12, s0,s1);
            racc(u0, k20,k21,k22, s0,s1);
            const int y = yu - 1;
            const bool act = (y >= ytop - (FDv-1)) && (y <= ytop + R + FDv - 2)
                          && ((unsigned)y < HH);
            v0[0] = act ? fmaf(tau[0], fh[0].x - s0, u1.b) : 0.f;
            v1[0] = act ? fmaf(tau[0], fh[0].y - s1, u1.c) : 0.f;
        }
#pragma unroll
        for (int j = 2; j <= FDv; ++j) {
            float s0 = 0.f, s1 = 0.f;
            racc(ltp[j-2], k00,k01,k02, s0,s1);
            racc(lmd[j-2], k10,k11,k12, s0,s1);
            racc(am[j-2],  k20,k21,k22, s0,s1);
            const int y = yu - (2*j - 1);
            const float2 fv = fh[2*(j-1)];
            if (j < FDv) {
                const bool act = (y >= ytop - (FDv-j)) && (y <= ytop + R + FDv - j - 1)
                              && ((unsigned)y < HH);
                v0[j-1] = act ? fmaf(tau[j-1], fv.x - s0, lmd[j-2].b) : 0.f;
                v1[j-1] = act ? fmaf(tau[j-1], fv.y - s1, lmd[j-2].c) : 0.f;
            } else {
                if (y >= ytop && y < ytop + R) {
                    const float o0 = fmaf(tau[FDv-1], fv.x - s0, lmd[j-2].b);
                    const float o1 = fmaf(tau[FDv-1], fv.y - s1, lmd[j-2].c);
                    *reinterpret_cast<float2*>(op + (size_t)y * WW + c2) =
                        make_float2(o0, o1);
                }
            }
        }
#pragma unroll
        for (int l = 0; l < FDv - 1; ++l) {
            re[l][wpar][1 + t] = v0[l];
            ro[l][wpar][1 + t] = v1[l];
            ltp[l] = lmd[l]; lmd[l] = am[l];
            own0[l] = v0[l]; own1[l] = v1[l];
        }
        u2 = u1; u1 = u0; u0 = un;
#pragma unroll
        for (int k = 2 * FDv - 2; k > 0; --k) fh[k] = fh[k - 1];
        fh[0] = fn;
        softbar();
    }
}

extern "C" void kernel_launch(void* const* d_in, const int* in_sizes, int n_in,
                              void* d_out, int out_size, void* d_ws, size_t ws_size,
                              hipStream_t stream)
{
    const float* x_in = (const float*)d_in[0];
    const float* f_in = (const float*)d_in[1];
    const float* k_in = (const float*)d_in[2];
    const float* u_in = (const float*)d_in[3];
    float* out = (float*)d_out;

    float* bufA = (float*)d_ws;                 // 64 MB field
    float* pmW0 = bufA + (size_t)BB * PLANE;
    float* pmW1 = pmW0 + BB * NSTRIPE;
    float* pmZ  = pmW1 + BB * NSTRIPE;
    float* taus = pmZ  + BB * NSTRIPE;          // [15*BB]

    dim3 blk(256), grd(NSTRIPE, BB);

    // ---- 2 fused power passes (10 levels each = 20 iterations) ----
    conv_fusedN<10><<<grd, blk, 0, stream>>>(u_in, k_in, nullptr, bufA, pmW0, pmZ);
    conv_fusedN<10><<<grd, blk, 0, stream>>>(bufA, k_in, pmW0, nullptr, pmW1, pmZ);

    // m = max|v20| / max|v19|
    tau_fused<<<BB, 64, 0, stream>>>(pmZ, pmW1, taus);

    // ---- 2 fused Chebyshev passes (8 + 7 levels = 15) ----
    cheby_fusedN<8><<<grd, blk, 0, stream>>>(x_in, f_in, k_in, taus, bufA);
    cheby_fusedN<7><<<grd, blk, 0, stream>>>(bufA, f_in, k_in, taus + 8 * BB, out);
}